// Round 4
// baseline (377.671 us; speedup 1.0000x reference)
//
#include <hip/hip_runtime.h>
#include <math.h>

// B=batch, S=state_dim, D=image channels, N=spatial positions
#define BB 128
#define SS 1024
#define DD 512
#define NN 784
#define NCHK 4      // n-chunks per batch for fused split-softmax
#define NC 196      // n per chunk (= 49 float4)

__device__ __forceinline__ float wave_reduce_sum(float x) {
#pragma unroll
  for (int m = 32; m > 0; m >>= 1) x += __shfl_xor(x, m, 64);
  return x;
}
__device__ __forceinline__ float wave_reduce_max(float x) {
#pragma unroll
  for (int m = 32; m > 0; m >>= 1) x = fmaxf(x, __shfl_xor(x, m, 64));
  return x;
}

// K1: v[k] = sum_j Wa[j] * Wc[j, k],  k in [0, 2D).  v pre-zeroed by memsetAsync.
__global__ void k1_v(const float* __restrict__ Wa, const float* __restrict__ Wc,
                     float* __restrict__ v) {
  int k = blockIdx.x * 256 + threadIdx.x;
  int j0 = blockIdx.y * 32;
  float acc = 0.f;
#pragma unroll
  for (int j = 0; j < 32; ++j)
    acc += Wa[j0 + j] * Wc[(size_t)(j0 + j) * (2 * DD) + k];
  atomicAdd(&v[k], acc);
}

// K2: w[b,d] = (in_state[b,:]·Wq[d,:] + bq[d]) * v[d] + v[D+d]
// grid (16 d-chunks, B), block 256 (4 waves x 8 rows), loads before reduces.
__global__ void k2_w(const float* __restrict__ in_state, const float* __restrict__ Wq,
                     const float* __restrict__ bq, const float* __restrict__ v,
                     float* __restrict__ w) {
  __shared__ float st[SS];
  int b = blockIdx.y;
  int t = threadIdx.x, lane = t & 63, wv = t >> 6;
  ((float4*)st)[t] = ((const float4*)(in_state + (size_t)b * SS))[t];
  __syncthreads();
  const float4* st4 = (const float4*)st;
  float4 s0 = st4[lane], s1 = st4[lane + 64], s2 = st4[lane + 128], s3 = st4[lane + 192];
  int d0 = blockIdx.x * 32 + wv * 8;
  float acc[8];
#pragma unroll
  for (int r = 0; r < 8; ++r) {
    const float4* q4 = (const float4*)(Wq + (size_t)(d0 + r) * SS);
    float4 a0 = q4[lane], a1 = q4[lane + 64], a2 = q4[lane + 128], a3 = q4[lane + 192];
    acc[r] = a0.x * s0.x + a0.y * s0.y + a0.z * s0.z + a0.w * s0.w
           + a1.x * s1.x + a1.y * s1.y + a1.z * s1.z + a1.w * s1.w
           + a2.x * s2.x + a2.y * s2.y + a2.z * s2.z + a2.w * s2.w
           + a3.x * s3.x + a3.y * s3.y + a3.z * s3.z + a3.w * s3.w;
  }
#pragma unroll
  for (int r = 0; r < 8; ++r) acc[r] = wave_reduce_sum(acc[r]);
  if (lane == 0) {
#pragma unroll
    for (int r = 0; r < 8; ++r) {
      int d = d0 + r;
      w[(size_t)b * DD + d] = (acc[r] + bq[d]) * v[d] + v[DD + d];
    }
  }
}

// K3 fused, register-resident: one (b, n-chunk) block sees all D rows for its
// 196 columns. Block 1024 = 16 waves x 32 d-rows; each lane keeps its 32
// float4 chunk rows IN REGISTERS (128 VGPRs) across the softmax, so phase 2
// (pooled partials) does zero memory reads. Image is read once from HBM.
// grid (NCHK, B) = 512 blocks.
__global__ void k3_fused(const float* __restrict__ image, const float* __restrict__ w,
                         float* __restrict__ P_part, float* __restrict__ mZ_part) {
  __shared__ float w_lds[DD];
  __shared__ float4 red[16][49];
  __shared__ float4 u_lds[49];
  __shared__ float p_s[DD];
  int b = blockIdx.y, c = blockIdx.x;
  int t = threadIdx.x, lane = t & 63, wv = t >> 6;
  if (t < DD) w_lds[t] = w[(size_t)b * DD + t];
  __syncthreads();
  const float4* img4 = (const float4*)image + (size_t)b * DD * 49 * NCHK;
  int d0 = wv * 32;
  const float4* pbase = img4 + (size_t)d0 * (49 * NCHK) + c * 49 + (lane < 49 ? lane : 48);
  // ---- phase 1: load 32 rows into registers, accumulate logit partials ----
  float4 x[32];
#pragma unroll
  for (int i = 0; i < 32; ++i) x[i] = pbase[(size_t)i * (49 * NCHK)];
  float4 acc = {0, 0, 0, 0};
#pragma unroll
  for (int i = 0; i < 32; ++i) {
    float wd = w_lds[d0 + i];
    acc.x += wd * x[i].x; acc.y += wd * x[i].y;
    acc.z += wd * x[i].z; acc.w += wd * x[i].w;
  }
  if (lane < 49) red[wv][lane] = acc;
  __syncthreads();
  // ---- wave 0: combine across waves, chunk softmax ----
  if (wv == 0) {
    float4 l4 = {0, 0, 0, 0};
    float lm = -1e30f;
    if (lane < 49) {
#pragma unroll
      for (int v16 = 0; v16 < 16; ++v16) {
        float4 r = red[v16][lane];
        l4.x += r.x; l4.y += r.y; l4.z += r.z; l4.w += r.w;
      }
      lm = fmaxf(fmaxf(l4.x, l4.y), fmaxf(l4.z, l4.w));
    }
    float m = wave_reduce_max(lm);
    float zs = 0.f;
    if (lane < 49) {
      float4 u4;
      u4.x = __expf(l4.x - m); u4.y = __expf(l4.y - m);
      u4.z = __expf(l4.z - m); u4.w = __expf(l4.w - m);
      zs = u4.x + u4.y + u4.z + u4.w;
      u_lds[lane] = u4;
    }
    float Z = wave_reduce_sum(zs);
    if (lane == 0) {
      mZ_part[((size_t)b * NCHK + c) * 2 + 0] = m;
      mZ_part[((size_t)b * NCHK + c) * 2 + 1] = Z;
    }
  }
  __syncthreads();
  // ---- phase 2: pooled partials from registers (no memory reads) ----
  float4 u4 = {0, 0, 0, 0};
  if (lane < 49) u4 = u_lds[lane];
#pragma unroll
  for (int i = 0; i < 32; ++i) {
    float part = 0.f;
    if (lane < 49)
      part = u4.x * x[i].x + u4.y * x[i].y + u4.z * x[i].z + u4.w * x[i].w;
    part = wave_reduce_sum(part);
    if (lane == 0) p_s[d0 + i] = part;
  }
  __syncthreads();
  if (t < DD) P_part[((size_t)b * NCHK + c) * DD + t] = p_s[t];
}

// K6: combine chunk partials -> pooled (in LDS), then out[b,s] = pooled·Wo[s,:] + bo[s]
// grid (32 s-chunks, B), block 256 (4 waves x 8 rows)
__global__ void k6_out(const float* __restrict__ P_part, const float* __restrict__ mZ_part,
                       const float* __restrict__ Wo, const float* __restrict__ bo,
                       float* __restrict__ out) {
  __shared__ float p_s[DD];
  int b = blockIdx.y, t = threadIdx.x, lane = t & 63, wv = t >> 6;
  // reconstruct pooled[b, :] from the 4 chunk partials (L2-resident, 8 KB/b)
  float mc[NCHK], Zc[NCHK];
  float M = -1e30f;
#pragma unroll
  for (int c = 0; c < NCHK; ++c) {
    mc[c] = mZ_part[((size_t)b * NCHK + c) * 2 + 0];
    Zc[c] = mZ_part[((size_t)b * NCHK + c) * 2 + 1];
    M = fmaxf(M, mc[c]);
  }
  float Z = 0.f, al[NCHK];
#pragma unroll
  for (int c = 0; c < NCHK; ++c) { al[c] = __expf(mc[c] - M); Z += al[c] * Zc[c]; }
  float inv = 1.0f / Z;
  {
    float2 s = {0, 0};
    const float2* pp = (const float2*)(P_part + (size_t)b * NCHK * DD);
#pragma unroll
    for (int c = 0; c < NCHK; ++c) {
      float2 p = pp[c * (DD / 2) + t];
      s.x += al[c] * p.x; s.y += al[c] * p.y;
    }
    ((float2*)p_s)[t] = make_float2(s.x * inv, s.y * inv);
  }
  __syncthreads();
  const float4* p4 = (const float4*)p_s;
  float4 p0 = p4[lane], p1 = p4[lane + 64];
  int s0 = blockIdx.x * 32 + wv * 8;
  float acc[8];
#pragma unroll
  for (int r = 0; r < 8; ++r) {
    const float4* wo4 = (const float4*)(Wo + (size_t)(s0 + r) * DD);
    float4 x0 = wo4[lane], x1 = wo4[lane + 64];
    acc[r] = x0.x * p0.x + x0.y * p0.y + x0.z * p0.z + x0.w * p0.w
           + x1.x * p1.x + x1.y * p1.y + x1.z * p1.z + x1.w * p1.w;
  }
#pragma unroll
  for (int r = 0; r < 8; ++r) acc[r] = wave_reduce_sum(acc[r]);
  if (lane == 0) {
#pragma unroll
    for (int r = 0; r < 8; ++r) out[(size_t)b * SS + s0 + r] = acc[r] + bo[s0 + r];
  }
}

extern "C" void kernel_launch(void* const* d_in, const int* in_sizes, int n_in,
                              void* d_out, int out_size, void* d_ws, size_t ws_size,
                              hipStream_t stream) {
  const float* in_state = (const float*)d_in[0];
  const float* image    = (const float*)d_in[1];
  const float* Wq       = (const float*)d_in[2];
  const float* bq       = (const float*)d_in[3];
  const float* Wc       = (const float*)d_in[4];
  const float* Wa       = (const float*)d_in[6];
  const float* Wo       = (const float*)d_in[8];
  const float* bo       = (const float*)d_in[9];
  float* out = (float*)d_out;

  // workspace layout (floats): ~1.3 MB total
  float* ws      = (float*)d_ws;
  float* v       = ws;                               // 2D           = 1024
  float* w       = v + 2 * DD;                       // B*D          = 65536
  float* P_part  = w + BB * DD;                      // B*NCHK*D     = 262144
  float* mZ_part = P_part + (size_t)BB * NCHK * DD;  // B*NCHK*2     = 1024

  hipMemsetAsync(v, 0, 2 * DD * sizeof(float), stream);
  k1_v<<<dim3(4, 16), 256, 0, stream>>>(Wa, Wc, v);
  k2_w<<<dim3(16, BB), 256, 0, stream>>>(in_state, Wq, bq, v, w);
  k3_fused<<<dim3(NCHK, BB), 1024, 0, stream>>>(image, w, P_part, mZ_part);
  k6_out<<<dim3(32, BB), 256, 0, stream>>>(P_part, mZ_part, Wo, bo, out);
}

// Round 5
// 377.536 us; speedup vs baseline: 1.0004x; 1.0004x over previous
//
#include <hip/hip_runtime.h>
#include <math.h>

// B=batch, S=state_dim, D=image channels, N=spatial positions
#define BB 128
#define SS 1024
#define DD 512
#define NN 784
#define NF4 196    // float4 per image row

__device__ __forceinline__ float wave_reduce_sum(float x) {
#pragma unroll
  for (int m = 32; m > 0; m >>= 1) x += __shfl_xor(x, m, 64);
  return x;
}
__device__ __forceinline__ float wave_reduce_max(float x) {
#pragma unroll
  for (int m = 32; m > 0; m >>= 1) x = fmaxf(x, __shfl_xor(x, m, 64));
  return x;
}

// K1: v[k] = sum_j Wa[j] * Wc[j,k], k in [0,2D). v pre-zeroed by memsetAsync.
__global__ void k1_v(const float* __restrict__ Wa, const float* __restrict__ Wc,
                     float* __restrict__ v) {
  int k = blockIdx.x * 256 + threadIdx.x;
  int j0 = blockIdx.y * 32;
  float acc = 0.f;
#pragma unroll
  for (int j = 0; j < 32; ++j)
    acc += Wa[j0 + j] * Wc[(size_t)(j0 + j) * (2 * DD) + k];
  atomicAdd(&v[k], acc);
}

// K2: w[b,d] = (in_state[b,:]·Wq[d,:] + bq[d]) * v[d] + v[D+d]
__global__ void k2_w(const float* __restrict__ in_state, const float* __restrict__ Wq,
                     const float* __restrict__ bq, const float* __restrict__ v,
                     float* __restrict__ w) {
  __shared__ float st[SS];
  int b = blockIdx.y;
  int t = threadIdx.x, lane = t & 63, wv = t >> 6;
  ((float4*)st)[t] = ((const float4*)(in_state + (size_t)b * SS))[t];
  __syncthreads();
  const float4* st4 = (const float4*)st;
  float4 s0 = st4[lane], s1 = st4[lane + 64], s2 = st4[lane + 128], s3 = st4[lane + 192];
  int d0 = blockIdx.x * 32 + wv * 8;
  float acc[8];
#pragma unroll
  for (int r = 0; r < 8; ++r) {
    const float4* q4 = (const float4*)(Wq + (size_t)(d0 + r) * SS);
    float4 a0 = q4[lane], a1 = q4[lane + 64], a2 = q4[lane + 128], a3 = q4[lane + 192];
    acc[r] = a0.x * s0.x + a0.y * s0.y + a0.z * s0.z + a0.w * s0.w
           + a1.x * s1.x + a1.y * s1.y + a1.z * s1.z + a1.w * s1.w
           + a2.x * s2.x + a2.y * s2.y + a2.z * s2.z + a2.w * s2.w
           + a3.x * s3.x + a3.y * s3.y + a3.z * s3.z + a3.w * s3.w;
  }
#pragma unroll
  for (int r = 0; r < 8; ++r) acc[r] = wave_reduce_sum(acc[r]);
  if (lane == 0) {
#pragma unroll
    for (int r = 0; r < 8; ++r) {
      int d = d0 + r;
      w[(size_t)b * DD + d] = (acc[r] + bq[d]) * v[d] + v[DD + d];
    }
  }
}

// K3: logits[b,n] += sum over 32-row d-group of w[b,d]*image[b,d,n]
// grid (16 d-groups, B) = 2048 blocks, block 256 (4 waves x 8 rows).
// 28 independent loads per lane upfront, no spills (VGPR ~130 < 512 cap),
// cross-wave LDS combine, one atomicAdd per (block, n). logits pre-zeroed.
__global__ void k3_logits(const float* __restrict__ image, const float* __restrict__ w,
                          float* __restrict__ logits) {
  __shared__ float4 red4[4][NF4];   // 12.5 KB
  int b = blockIdx.y, g = blockIdx.x;
  int t = threadIdx.x, lane = t & 63, wv = t >> 6;
  int d0 = g * 32 + wv * 8;
  const float* wp = w + (size_t)b * DD + d0;
  float wr[8];
#pragma unroll
  for (int r = 0; r < 8; ++r) wr[r] = wp[r];   // wave-uniform broadcast loads
  const float4* base = (const float4*)image + ((size_t)b * DD + d0) * NF4;
  float4 x0[8], x1[8], x2[8];
#pragma unroll
  for (int r = 0; r < 8; ++r) {
    const float4* row = base + (size_t)r * NF4;
    x0[r] = row[lane];
    x1[r] = row[lane + 64];
    x2[r] = row[lane + 128];
  }
  float4 a0 = {0,0,0,0}, a1 = {0,0,0,0}, a2 = {0,0,0,0}, a3 = {0,0,0,0};
  if (lane < 4) {
#pragma unroll
    for (int r = 0; r < 8; ++r) {
      float4 x3 = base[(size_t)r * NF4 + 192 + lane];
      float wd = wr[r];
      a3.x += wd * x3.x; a3.y += wd * x3.y; a3.z += wd * x3.z; a3.w += wd * x3.w;
    }
  }
#pragma unroll
  for (int r = 0; r < 8; ++r) {
    float wd = wr[r];
    a0.x += wd * x0[r].x; a0.y += wd * x0[r].y; a0.z += wd * x0[r].z; a0.w += wd * x0[r].w;
    a1.x += wd * x1[r].x; a1.y += wd * x1[r].y; a1.z += wd * x1[r].z; a1.w += wd * x1[r].w;
    a2.x += wd * x2[r].x; a2.y += wd * x2[r].y; a2.z += wd * x2[r].z; a2.w += wd * x2[r].w;
  }
  red4[wv][lane] = a0;
  red4[wv][lane + 64] = a1;
  red4[wv][lane + 128] = a2;
  if (lane < 4) red4[wv][192 + lane] = a3;
  __syncthreads();
  const float* redf = (const float*)red4;   // wave stride = NF4*4 = 784 floats
  float* lg = logits + (size_t)b * NN;
  for (int n = t; n < NN; n += 256) {
    float s = redf[n] + redf[NN + n] + redf[2 * NN + n] + redf[3 * NN + n];
    atomicAdd(&lg[n], s);
  }
}

// K5: per-block softmax recompute (logits are L2/L3-hot, 3 KB/b) then
// pooled[b,d] = (1/Z) * sum_n exp(l_n - m) * image[b,d,n]
// grid (16 d-groups, B) = 2048 blocks, block 256 (4 waves x 8 rows), no spills.
__global__ void k5_pooled(const float* __restrict__ image, const float* __restrict__ logits,
                          float* __restrict__ pooled) {
  __shared__ float att[NN];
  __shared__ float wredm[4];
  __shared__ float wredz[4];
  int b = blockIdx.y, g = blockIdx.x;
  int t = threadIdx.x, lane = t & 63, wv = t >> 6;
  // ---- softmax numerators in LDS, Z as block-uniform scalar ----
  const float* lg = logits + (size_t)b * NN;
  float l0 = lg[t], l1 = lg[t + 256], l2 = lg[t + 512];
  float l3 = (t < NN - 768) ? lg[t + 768] : -1e30f;
  float lm = fmaxf(fmaxf(l0, l1), fmaxf(l2, l3));
  lm = wave_reduce_max(lm);
  if (lane == 0) wredm[wv] = lm;
  __syncthreads();
  float m = fmaxf(fmaxf(wredm[0], wredm[1]), fmaxf(wredm[2], wredm[3]));
  float u0 = __expf(l0 - m), u1 = __expf(l1 - m), u2 = __expf(l2 - m);
  float u3 = (t < NN - 768) ? __expf(l3 - m) : 0.f;
  att[t] = u0; att[t + 256] = u1; att[t + 512] = u2;
  if (t < NN - 768) att[t + 768] = u3;
  float zs = u0 + u1 + u2 + u3;
  zs = wave_reduce_sum(zs);
  if (lane == 0) wredz[wv] = zs;
  __syncthreads();
  float invZ = 1.0f / (wredz[0] + wredz[1] + wredz[2] + wredz[3]);
  const float4* att4 = (const float4*)att;
  float4 aa0 = att4[lane], aa1 = att4[lane + 64], aa2 = att4[lane + 128];
  // ---- stream 32 contiguous rows, 28 loads upfront, row dots ----
  int d0 = g * 32 + wv * 8;
  const float4* base = (const float4*)image + ((size_t)b * DD + d0) * NF4;
  float4 x0[8], x1[8], x2[8];
#pragma unroll
  for (int r = 0; r < 8; ++r) {
    const float4* row = base + (size_t)r * NF4;
    x0[r] = row[lane];
    x1[r] = row[lane + 64];
    x2[r] = row[lane + 128];
  }
  float acc[8];
#pragma unroll
  for (int r = 0; r < 8; ++r)
    acc[r] = x0[r].x * aa0.x + x0[r].y * aa0.y + x0[r].z * aa0.z + x0[r].w * aa0.w
           + x1[r].x * aa1.x + x1[r].y * aa1.y + x1[r].z * aa1.z + x1[r].w * aa1.w
           + x2[r].x * aa2.x + x2[r].y * aa2.y + x2[r].z * aa2.z + x2[r].w * aa2.w;
  if (lane < 4) {
    float4 aa3 = att4[192 + lane];
#pragma unroll
    for (int r = 0; r < 8; ++r) {
      float4 x3 = base[(size_t)r * NF4 + 192 + lane];
      acc[r] += x3.x * aa3.x + x3.y * aa3.y + x3.z * aa3.z + x3.w * aa3.w;
    }
  }
#pragma unroll
  for (int r = 0; r < 8; ++r) acc[r] = wave_reduce_sum(acc[r]);
  if (lane == 0) {
#pragma unroll
    for (int r = 0; r < 8; ++r) pooled[(size_t)b * DD + d0 + r] = acc[r] * invZ;
  }
}

// K6: out[b,s] = pooled[b,:]·Wo[s,:] + bo[s]; Wo rows held in registers and
// reused across 8 batches per block to cut Wo L2/L3 re-reads 8x.
// grid (32 s-chunks, 16 b-groups) = 512 blocks, block 256 (4 waves x 8 rows).
__global__ void k6_out(const float* __restrict__ pooled, const float* __restrict__ Wo,
                       const float* __restrict__ bo, float* __restrict__ out) {
  int sg = blockIdx.x, bg = blockIdx.y;
  int t = threadIdx.x, lane = t & 63, wv = t >> 6;
  int s0 = sg * 32 + wv * 8;
  float4 w0[8], w1[8];
#pragma unroll
  for (int r = 0; r < 8; ++r) {
    const float4* wo4 = (const float4*)(Wo + (size_t)(s0 + r) * DD);
    w0[r] = wo4[lane];
    w1[r] = wo4[lane + 64];
  }
  float bov[8];
#pragma unroll
  for (int r = 0; r < 8; ++r) bov[r] = bo[s0 + r];
  for (int bi = 0; bi < 8; ++bi) {
    int b = bg * 8 + bi;
    const float4* p4 = (const float4*)(pooled + (size_t)b * DD);
    float4 p0 = p4[lane], p1 = p4[lane + 64];
    float acc[8];
#pragma unroll
    for (int r = 0; r < 8; ++r)
      acc[r] = w0[r].x * p0.x + w0[r].y * p0.y + w0[r].z * p0.z + w0[r].w * p0.w
             + w1[r].x * p1.x + w1[r].y * p1.y + w1[r].z * p1.z + w1[r].w * p1.w;
#pragma unroll
    for (int r = 0; r < 8; ++r) acc[r] = wave_reduce_sum(acc[r]);
    if (lane == 0) {
#pragma unroll
      for (int r = 0; r < 8; ++r) out[(size_t)b * SS + s0 + r] = acc[r] + bov[r];
    }
  }
}

extern "C" void kernel_launch(void* const* d_in, const int* in_sizes, int n_in,
                              void* d_out, int out_size, void* d_ws, size_t ws_size,
                              hipStream_t stream) {
  const float* in_state = (const float*)d_in[0];
  const float* image    = (const float*)d_in[1];
  const float* Wq       = (const float*)d_in[2];
  const float* bq       = (const float*)d_in[3];
  const float* Wc       = (const float*)d_in[4];
  const float* Wa       = (const float*)d_in[6];
  const float* Wo       = (const float*)d_in[8];
  const float* bo       = (const float*)d_in[9];
  float* out = (float*)d_out;

  // workspace layout (floats); v+logits adjacent -> one zeroing memset
  float* ws     = (float*)d_ws;
  float* v      = ws;                          // 2D      = 1024
  float* logits = v + 2 * DD;                  // B*N     = 100352
  float* w      = logits + (size_t)BB * NN;    // B*D     = 65536
  float* pooled = w + (size_t)BB * DD;         // B*D     = 65536

  hipMemsetAsync(ws, 0, (2 * DD + (size_t)BB * NN) * sizeof(float), stream);
  k1_v<<<dim3(4, 16), 256, 0, stream>>>(Wa, Wc, v);
  k2_w<<<dim3(16, BB), 256, 0, stream>>>(in_state, Wq, bq, v, w);
  k3_logits<<<dim3(16, BB), 256, 0, stream>>>(image, w, logits);
  k5_pooled<<<dim3(16, BB), 256, 0, stream>>>(image, logits, pooled);
  k6_out<<<dim3(32, 16), 256, 0, stream>>>(pooled, Wo, bo, out);
}